// Round 2
// baseline (618.023 us; speedup 1.0000x reference)
//
#include <hip/hip_runtime.h>

// AKConv (all fp32): x[8,128,80,80] -> offset conv(3x3,10ch) -> bilinear sample n=5
//   -> 1xn conv (GEMM M=256,K=640,N=51200) -> BN + SiLU -> out[8,256,80,80]

#define Bsz 8
#define C1 128
#define C2 256
#define Hdim 80
#define Wdim 80
#define HW 6400
#define NP 5
#define KTOT 640      // C1 * NP; K index = c*5 + k (matches cw [o][c][k][1] layout)

// ---- workspace layout (bytes) ----
#define NPOS (Bsz*NP*HW)                 // 256000 sampling points
#define WS_IDX4 0                        // int4[NPOS]   4.1 MB
#define WS_WGT4 (WS_IDX4 + NPOS*16)      // float4[NPOS] 4.1 MB
#define WS_BNS  (WS_WGT4 + NPOS*16)      // float[256] scale
#define WS_BNT  (WS_BNS + 256*4)         // float[256] shift

// ---------------- K0: fold BN into scale/shift ----------------
__global__ __launch_bounds__(256) void k_pre(
    const float* __restrict__ gam, const float* __restrict__ bet,
    const float* __restrict__ mu, const float* __restrict__ var,
    float* __restrict__ bns, float* __restrict__ bnt) {
  int i = threadIdx.x;
  float s = gam[i] * rsqrtf(var[i] + 1e-5f);
  bns[i] = s;
  bnt[i] = bet[i] - mu[i] * s;
}

// -------- K1: offset conv (3x3, pad 1) + bilinear idx/weights per (b,k,p) ----
__global__ __launch_bounds__(256) void k_offset(
    const float* __restrict__ x,
    const float* __restrict__ pw, const float* __restrict__ pb,
    int4* __restrict__ idx4, float4* __restrict__ wgt4) {
  int tid = blockIdx.x * 256 + threadIdx.x;   // 51200 threads, one per (b,p)
  int b = tid / HW, p = tid % HW;
  int h = p / Wdim, w = p % Wdim;

  float off[10];
#pragma unroll
  for (int oc = 0; oc < 10; ++oc) off[oc] = pb[oc];

  const float* xb = x + (size_t)b * C1 * HW;
  for (int ci = 0; ci < C1; ++ci) {
    float xv[9];
#pragma unroll
    for (int t = 0; t < 9; ++t) {
      int hh = h + t / 3 - 1, ww = w + t % 3 - 1;
      bool ok = ((unsigned)hh < Hdim) && ((unsigned)ww < Wdim);
      xv[t] = ok ? xb[ci * HW + hh * Wdim + ww] : 0.f;
    }
#pragma unroll
    for (int oc = 0; oc < 10; ++oc) {
      const float* wp = pw + (oc * C1 + ci) * 9;   // wave-uniform -> s_loads
      float s = 0.f;
#pragma unroll
      for (int t = 0; t < 9; ++t) s = fmaf(xv[t], wp[t], s);
      off[oc] += s;
    }
  }

  const float pnx[5] = {0.f, 0.f, 1.f, 1.f, 2.f};
  const float pny[5] = {0.f, 1.f, 0.f, 1.f, 0.f};
#pragma unroll
  for (int k = 0; k < NP; ++k) {
    float px = off[k] + (float)h + pnx[k];
    float py = off[5 + k] + (float)w + pny[k];
    float pf = floorf(px), qf = floorf(py);
    float x0 = fminf(fmaxf(pf, 0.f), 79.f);
    float x1 = fminf(fmaxf(pf + 1.f, 0.f), 79.f);
    float y0 = fminf(fmaxf(qf, 0.f), 79.f);
    float y1 = fminf(fmaxf(qf + 1.f, 0.f), 79.f);
    float pxc = fminf(fmaxf(px, 0.f), 79.f);
    float pyc = fminf(fmaxf(py, 0.f), 79.f);
    float wx0 = 1.f + (x0 - pxc), wx1 = 1.f - (x1 - pxc);
    float wy0 = 1.f + (y0 - pyc), wy1 = 1.f - (y1 - pyc);
    int ix0 = (int)x0, ix1 = (int)x1, iy0 = (int)y0, iy1 = (int)y1;
    int g = (b * NP + k) * HW + p;
    idx4[g] = make_int4(ix0 * Wdim + iy0, ix1 * Wdim + iy1,
                        ix0 * Wdim + iy1, ix1 * Wdim + iy0);
    wgt4[g] = make_float4(wx0 * wy0, wx1 * wy1, wx0 * wy1, wx1 * wy0);
  }
}

// -------- K3: fused gather + GEMM + BN + SiLU ----------------------------
// C[m=oc, n=pixel] = sum_K cw[m,K] * xoff[K,n];  K = c*5+k
#define MT 128
#define NT 128
#define KC 16
#define LDA 132   // padded row (floats): 16B-aligned rows, breaks conflicts

__global__ __launch_bounds__(256) void k_main(
    const float* __restrict__ x, const float* __restrict__ cw,
    const int4* __restrict__ idx4, const float4* __restrict__ wgt4,
    const float* __restrict__ bns, const float* __restrict__ bnt,
    float* __restrict__ out) {
  __shared__ __align__(16) float As[KC * LDA];
  __shared__ __align__(16) float Bs[KC * LDA];
  __shared__ int4   sIdx[NP * NT];
  __shared__ float4 sWgt[NP * NT];

  const int tx = threadIdx.x;
  const int oc0 = blockIdx.x * MT;          // 0 or 128
  const int px0 = blockIdx.y * NT;          // global pixel tile (never crosses b)
  const int b = px0 / HW;
  const int pbase = px0 % HW;
  const float* xb = x + (size_t)b * C1 * HW;

  // stage the 5 x 128 sampling tables for this pixel tile
  for (int i = tx; i < NP * NT; i += 256) {
    int k = i >> 7, j = i & 127;
    int g = (b * NP + k) * HW + pbase + j;
    sIdx[i] = idx4[g];
    sWgt[i] = wgt4[g];
  }

  float acc[8][8];
#pragma unroll
  for (int i = 0; i < 8; ++i)
#pragma unroll
    for (int j = 0; j < 8; ++j) acc[i][j] = 0.f;

  const int tm = tx >> 4, tn = tx & 15;     // 16x16 thread grid, 8x8 regs each

  for (int kt = 0; kt < KTOT; kt += KC) {
    __syncthreads();   // also covers sIdx/sWgt staging on first iteration
    // ---- stage A tile: As[kk][m] = cw[oc0+m][kt+kk]
#pragma unroll
    for (int it = 0; it < 8; ++it) {
      int e = tx + it * 256;
      int m = e >> 4, kk = e & 15;
      As[kk * LDA + m] = cw[(size_t)(oc0 + m) * KTOT + kt + kk];
    }
    // ---- stage B tile: Bs[kk][j] = bilinear-gathered xoff
#pragma unroll
    for (int it = 0; it < 8; ++it) {
      int e = tx + it * 256;                // consecutive lanes -> consecutive j
      int kk = e >> 7, j = e & 127;
      int Kg = kt + kk;
      int c = Kg / 5, k5 = Kg - 5 * c;      // wave-uniform
      const float* xc = xb + c * HW;
      int4   id = sIdx[k5 * NT + j];
      float4 wg = sWgt[k5 * NT + j];
      float v = wg.x * xc[id.x] + wg.y * xc[id.y]
              + wg.z * xc[id.z] + wg.w * xc[id.w];
      Bs[kk * LDA + j] = v;
    }
    __syncthreads();
    // ---- FMA on the tile
#pragma unroll
    for (int kk = 0; kk < KC; ++kk) {
      const float4 a0 = *(const float4*)&As[kk * LDA + tm * 8];
      const float4 a1 = *(const float4*)&As[kk * LDA + tm * 8 + 4];
      const float4 b0 = *(const float4*)&Bs[kk * LDA + tn * 8];
      const float4 b1 = *(const float4*)&Bs[kk * LDA + tn * 8 + 4];
      float av[8] = {a0.x, a0.y, a0.z, a0.w, a1.x, a1.y, a1.z, a1.w};
      float bv[8] = {b0.x, b0.y, b0.z, b0.w, b1.x, b1.y, b1.z, b1.w};
#pragma unroll
      for (int i = 0; i < 8; ++i)
#pragma unroll
        for (int j = 0; j < 8; ++j)
          acc[i][j] = fmaf(av[i], bv[j], acc[i][j]);
    }
  }

  // ---- epilogue: BN + SiLU, float4 stores
#pragma unroll
  for (int i = 0; i < 8; ++i) {
    int m = oc0 + tm * 8 + i;
    const float s = bns[m], t = bnt[m];
    float r[8];
#pragma unroll
    for (int j = 0; j < 8; ++j) {
      float y = fmaf(acc[i][j], s, t);
      r[j] = y * (1.f / (1.f + __expf(-y)));   // SiLU
    }
    float* op = out + ((size_t)(b * C2 + m)) * HW + pbase + tn * 8;
    *(float4*)(op)     = make_float4(r[0], r[1], r[2], r[3]);
    *(float4*)(op + 4) = make_float4(r[4], r[5], r[6], r[7]);
  }
}

extern "C" void kernel_launch(void* const* d_in, const int* in_sizes, int n_in,
                              void* d_out, int out_size, void* d_ws, size_t ws_size,
                              hipStream_t stream) {
  const float* x  = (const float*)d_in[0];
  const float* pw = (const float*)d_in[1];
  const float* pb = (const float*)d_in[2];
  const float* cw = (const float*)d_in[3];
  const float* bg = (const float*)d_in[4];
  const float* bb = (const float*)d_in[5];
  const float* bm = (const float*)d_in[6];
  const float* bv = (const float*)d_in[7];
  float* out = (float*)d_out;

  char* ws = (char*)d_ws;
  int4*   idx4 = (int4*)(ws + WS_IDX4);
  float4* wgt4 = (float4*)(ws + WS_WGT4);
  float*  bns  = (float*)(ws + WS_BNS);
  float*  bnt  = (float*)(ws + WS_BNT);

  k_pre<<<1, 256, 0, stream>>>(bg, bb, bm, bv, bns, bnt);
  k_offset<<<200, 256, 0, stream>>>(x, pw, pb, idx4, wgt4);
  k_main<<<dim3(2, 400), 256, 0, stream>>>(x, cw, idx4, wgt4, bns, bnt, out);
}

// Round 3
// 254.476 us; speedup vs baseline: 2.4286x; 2.4286x over previous
//
#include <hip/hip_runtime.h>
#include <hip/hip_bf16.h>

// AKConv fp32 in/out, bf16 MFMA core.
// x[8,128,80,80] -> offset conv(3x3,10ch) -> bilinear n=5 -> GEMM(M=256,K=640,N=51200)
//   as 20 chunks of K=32 (k-major reorder) via mfma_f32_16x16x32_bf16 -> BN+SiLU.

typedef __attribute__((ext_vector_type(8))) short short8;
typedef __attribute__((ext_vector_type(4))) float f32x4;

#define Bsz 8
#define C1 128
#define C2 256
#define HW 6400
#define NP 5

// ---- workspace layout (bytes) ----
#define NPOS (Bsz*NP*HW)                    // 256000 samples
#define WS_IDX4 0                           // int4[NPOS]  : 4 corner BYTE offsets into xT image
#define WS_WGT4 (WS_IDX4 + NPOS*16)         // float4[NPOS]
#define WS_XT   (WS_WGT4 + NPOS*16)         // ushort xT[8][6400][128]  13.1 MB
#define WS_ACW  (WS_XT + Bsz*HW*C1*2)       // ushort acw[163840] pre-swizzled A frags
#define WS_BNS  (WS_ACW + C2*C1*NP*2)
#define WS_BNT  (WS_BNS + 1024)

__device__ __forceinline__ unsigned short f2bf(float f) {
  __hip_bfloat16 h = __float2bfloat16(f);
  return reinterpret_cast<unsigned short&>(h);
}
__device__ __forceinline__ float bfu2f(unsigned short u) {
  unsigned int v = ((unsigned int)u) << 16;
  return reinterpret_cast<float&>(v);
}

// ---- K0: BN fold + A-operand pre-swizzle to MFMA fragment order -------------
// acw layout: [k][cc][mtile][lane][j]  (j contiguous 8 -> one 16B frag per lane)
//   element = cw[m][c][k], m = mtile*16 + (lane&15), c = cc*32 + (lane>>4)*8 + j
__global__ __launch_bounds__(256) void k_pre(
    const float* __restrict__ cw, const float* __restrict__ gam,
    const float* __restrict__ bet, const float* __restrict__ mu,
    const float* __restrict__ var,
    unsigned short* __restrict__ acw, float* __restrict__ bns,
    float* __restrict__ bnt) {
  int i = blockIdx.x * 256 + threadIdx.x;          // 640 blocks -> 163840
  int j = i & 7, lane = (i >> 3) & 63, mtile = (i >> 9) & 15;
  int cc = (i >> 13) & 3, k = i >> 15;
  int m = mtile * 16 + (lane & 15);
  int c = cc * 32 + (lane >> 4) * 8 + j;
  acw[i] = f2bf(cw[(m * C1 + c) * NP + k]);
  if (blockIdx.x == 0) {
    int t = threadIdx.x;
    float s = gam[t] * rsqrtf(var[t] + 1e-5f);
    bns[t] = s;
    bnt[t] = bet[t] - mu[t] * s;
  }
}

// ---- K-T: transpose x[b][c][hw] fp32 -> xT[b][hw][c] bf16 ------------------
__global__ __launch_bounds__(256) void k_trans(const float* __restrict__ x,
                                               unsigned short* __restrict__ xT) {
  int t = threadIdx.x;
  int cq = t & 3, pl = t >> 2;                     // 4 channel-quads x 64 pixels
  int gp = blockIdx.x * 64 + pl;                   // = b*HW + p
  int b = gp / HW, p = gp - b * HW;
  const float* xp = x + (size_t)b * C1 * HW + p;
  unsigned short v[32];
#pragma unroll
  for (int i = 0; i < 32; ++i)
    v[i] = f2bf(xp[(size_t)(cq * 32 + i) * HW]);
  uint4* dst = (uint4*)(xT + (size_t)gp * C1 + cq * 32);
#pragma unroll
  for (int q = 0; q < 4; ++q) dst[q] = *(uint4*)&v[q * 8];
}

// ---- K1: offset conv (3x3,pad1) + bilinear tables, 4-way channel split -----
__global__ __launch_bounds__(256) void k_offset(
    const float* __restrict__ x, const float* __restrict__ pw,
    const float* __restrict__ pb,
    int4* __restrict__ idx4, float4* __restrict__ wgt4) {
  __shared__ float red[4 * 64 * 10];
  int t = threadIdx.x;
  int j = t & 63, q = t >> 6;
  int gp = blockIdx.x * 64 + j;
  int b = gp / HW, p = gp - b * HW;
  int h = p / 80, w = p - h * 80;

  float off[10];
#pragma unroll
  for (int oc = 0; oc < 10; ++oc) off[oc] = 0.f;
  const float* xb = x + (size_t)b * C1 * HW;
  for (int ci = q * 32; ci < q * 32 + 32; ++ci) {
    float xv[9];
#pragma unroll
    for (int tt = 0; tt < 9; ++tt) {
      int hh = h + tt / 3 - 1, ww = w + tt % 3 - 1;
      bool ok = ((unsigned)hh < 80u) && ((unsigned)ww < 80u);
      xv[tt] = ok ? xb[ci * HW + hh * 80 + ww] : 0.f;
    }
#pragma unroll
    for (int oc = 0; oc < 10; ++oc) {
      const float* wo = pw + (oc * C1 + ci) * 9;   // wave-uniform
      float s = 0.f;
#pragma unroll
      for (int tt = 0; tt < 9; ++tt) s = fmaf(xv[tt], wo[tt], s);
      off[oc] += s;
    }
  }
#pragma unroll
  for (int oc = 0; oc < 10; ++oc) red[(q * 64 + j) * 10 + oc] = off[oc];
  __syncthreads();
  if (t < 64) {
    float o[10];
#pragma unroll
    for (int oc = 0; oc < 10; ++oc)
      o[oc] = pb[oc] + red[t * 10 + oc] + red[(64 + t) * 10 + oc]
            + red[(128 + t) * 10 + oc] + red[(192 + t) * 10 + oc];
    const float pnx[5] = {0.f, 0.f, 1.f, 1.f, 2.f};
    const float pny[5] = {0.f, 1.f, 0.f, 1.f, 0.f};
#pragma unroll
    for (int k = 0; k < NP; ++k) {
      float px = o[k] + (float)h + pnx[k];
      float py = o[5 + k] + (float)w + pny[k];
      float pf = floorf(px), qf = floorf(py);
      float x0 = fminf(fmaxf(pf, 0.f), 79.f);
      float x1 = fminf(fmaxf(pf + 1.f, 0.f), 79.f);
      float y0 = fminf(fmaxf(qf, 0.f), 79.f);
      float y1 = fminf(fmaxf(qf + 1.f, 0.f), 79.f);
      float pxc = fminf(fmaxf(px, 0.f), 79.f);
      float pyc = fminf(fmaxf(py, 0.f), 79.f);
      float wx0 = 1.f + (x0 - pxc), wx1 = 1.f - (x1 - pxc);
      float wy0 = 1.f + (y0 - pyc), wy1 = 1.f - (y1 - pyc);
      int ix0 = (int)x0, ix1 = (int)x1, iy0 = (int)y0, iy1 = (int)y1;
      int g = (b * NP + k) * HW + p;
      // byte offsets into xT image (pixel stride = C1*2 = 256 B)
      idx4[g] = make_int4((ix0 * 80 + iy0) << 8, (ix1 * 80 + iy1) << 8,
                          (ix0 * 80 + iy1) << 8, (ix1 * 80 + iy0) << 8);
      wgt4[g] = make_float4(wx0 * wy0, wx1 * wy1, wx0 * wy1, wx1 * wy0);
    }
  }
}

// ---- K3: fused gather + MFMA GEMM + BN + SiLU ------------------------------
// Block: M=256 (4 waves x 64 rows), N=64 pixels. 20 K-chunks of 32 (k-major).
__global__ __launch_bounds__(256) void k_main(
    const unsigned short* __restrict__ xT,
    const unsigned short* __restrict__ acw,
    const int4* __restrict__ idx4, const float4* __restrict__ wgt4,
    const float* __restrict__ bns, const float* __restrict__ bnt,
    float* __restrict__ out) {
  __shared__ unsigned short Bs[4 * 64 * 8];        // 4 n-tiles x 64 lanes x 16B
  __shared__ int4   sOff[NP * 64];
  __shared__ float4 sWgt[NP * 64];

  int t = threadIdx.x;
  int gp0 = blockIdx.x * 64;
  int b = gp0 / HW, pbase = gp0 - b * HW;

  for (int i = t; i < NP * 64; i += 256) {
    int k = i >> 6, n = i & 63;
    int g = (b * NP + k) * HW + pbase + n;
    sOff[i] = idx4[g];
    sWgt[i] = wgt4[g];
  }

  int wave = t >> 6, lane = t & 63;
  int gn = t >> 2, goct = t & 3;                   // gather: pixel, channel-octet
  const char* xTb = (const char*)(xT + (size_t)b * HW * C1);

  f32x4 acc[4][4];
#pragma unroll
  for (int mt = 0; mt < 4; ++mt)
#pragma unroll
    for (int nt = 0; nt < 4; ++nt) acc[mt][nt] = (f32x4)(0.f);

  for (int k = 0; k < NP; ++k) {
#pragma unroll
    for (int cc = 0; cc < 4; ++cc) {
      __syncthreads();
      // ---- stage B tile (32c x 64n) in B-fragment order
      int4   id = sOff[k * 64 + gn];
      float4 wg = sWgt[k * 64 + gn];
      int cb = cc * 64 + goct * 16;                // byte offset within pixel row
      union { uint4 v; unsigned short u[8]; } q0, q1, q2, q3, rr;
      q0.v = *(const uint4*)(xTb + id.x + cb);
      q1.v = *(const uint4*)(xTb + id.y + cb);
      q2.v = *(const uint4*)(xTb + id.z + cb);
      q3.v = *(const uint4*)(xTb + id.w + cb);
#pragma unroll
      for (int jj = 0; jj < 8; ++jj) {
        float f = wg.x * bfu2f(q0.u[jj]) + wg.y * bfu2f(q1.u[jj])
                + wg.z * bfu2f(q2.u[jj]) + wg.w * bfu2f(q3.u[jj]);
        rr.u[jj] = f2bf(f);
      }
      *(uint4*)(Bs + (((gn >> 4) * 64) + (goct << 4) + (gn & 15)) * 8) = rr.v;
      __syncthreads();
      // ---- compute: 4 m-tiles x 4 n-tiles of 16x16x32
      short8 bfr[4];
#pragma unroll
      for (int nt = 0; nt < 4; ++nt)
        bfr[nt] = *(const short8*)(Bs + (nt * 64 + lane) * 8);
      const unsigned short* ab =
          acw + (size_t)((((k * 4 + cc) * 16) + wave * 4) * 64 + lane) * 8;
#pragma unroll
      for (int mt = 0; mt < 4; ++mt) {
        short8 a = *(const short8*)(ab + mt * 64 * 8);
#pragma unroll
        for (int nt = 0; nt < 4; ++nt)
          acc[mt][nt] = __builtin_amdgcn_mfma_f32_16x16x32_bf16(
              a, bfr[nt], acc[mt][nt], 0, 0, 0);
      }
    }
  }

  // ---- epilogue: BN + SiLU
  int quad = lane >> 4, col = lane & 15;
#pragma unroll
  for (int mt = 0; mt < 4; ++mt) {
    int m0 = wave * 64 + mt * 16 + quad * 4;
#pragma unroll
    for (int r = 0; r < 4; ++r) {
      int m = m0 + r;
      float s = bns[m], sh = bnt[m];
      float* op = out + ((size_t)(b * C2 + m)) * HW + pbase;
#pragma unroll
      for (int nt = 0; nt < 4; ++nt) {
        float y = fmaf(acc[mt][nt][r], s, sh);
        op[nt * 16 + col] = y * (1.f / (1.f + __expf(-y)));
      }
    }
  }
}

extern "C" void kernel_launch(void* const* d_in, const int* in_sizes, int n_in,
                              void* d_out, int out_size, void* d_ws, size_t ws_size,
                              hipStream_t stream) {
  const float* x  = (const float*)d_in[0];
  const float* pw = (const float*)d_in[1];
  const float* pb = (const float*)d_in[2];
  const float* cw = (const float*)d_in[3];
  const float* bg = (const float*)d_in[4];
  const float* bb = (const float*)d_in[5];
  const float* bm = (const float*)d_in[6];
  const float* bv = (const float*)d_in[7];
  float* out = (float*)d_out;

  char* ws = (char*)d_ws;
  int4*           idx4 = (int4*)(ws + WS_IDX4);
  float4*         wgt4 = (float4*)(ws + WS_WGT4);
  unsigned short* xT   = (unsigned short*)(ws + WS_XT);
  unsigned short* acw  = (unsigned short*)(ws + WS_ACW);
  float*          bns  = (float*)(ws + WS_BNS);
  float*          bnt  = (float*)(ws + WS_BNT);

  k_pre<<<640, 256, 0, stream>>>(cw, bg, bb, bm, bv, acw, bns, bnt);
  k_trans<<<800, 256, 0, stream>>>(x, xT);
  k_offset<<<800, 256, 0, stream>>>(x, pw, pb, idx4, wgt4);
  k_main<<<800, 256, 0, stream>>>(xT, acw, idx4, wgt4, bns, bnt, out);
}

// Round 5
// 229.253 us; speedup vs baseline: 2.6958x; 1.1100x over previous
//
#include <hip/hip_runtime.h>
#include <hip/hip_bf16.h>

// AKConv fp32 in/out, bf16 MFMA everywhere.
//  k_pre   : BN fold + A-frag pre-swizzles: cw->acw (bf16), pw->apw hi/lo (double-bf16)
//  k_trans : x[b][c][hw] fp32 -> xT (bf16 hi) + xTlo (bf16 residual), channel-last
//  k_offset: 3x3 offset conv as double-bf16 MFMA GEMM (error ~2^-18, fp32-class;
//            needed because bilinear clip edges are discontinuous in px/py)
//  k_main  : fused gather + MFMA GEMM (M=256,K=640,N=51200) + BN + SiLU, dbuf

typedef __attribute__((ext_vector_type(8))) short short8;
typedef __attribute__((ext_vector_type(4))) float f32x4;

#define Bsz 8
#define C1 128
#define C2 256
#define HW 6400
#define NP 5

// ---- workspace layout (bytes) ----
#define NPOS (Bsz*NP*HW)                    // 256000 samples
#define WS_IDX4 0                           // int4[NPOS]: corner BYTE offsets into xT image
#define WS_WGT4 (WS_IDX4 + NPOS*16)         // float4[NPOS]
#define WS_XT   (WS_WGT4 + NPOS*16)         // ushort xT[8][6400][128]   13.1 MB (hi)
#define WS_XTLO (WS_XT + Bsz*HW*C1*2)       // ushort xTlo[8][6400][128] 13.1 MB (residual)
#define WS_ACW  (WS_XTLO + Bsz*HW*C1*2)     // ushort acw[163840]  (cw A-frags)
#define WS_APWH (WS_ACW + C2*C1*NP*2)       // ushort apw_hi[18432]
#define WS_APWL (WS_APWH + 18432*2)         // ushort apw_lo[18432]
#define WS_BNS  (WS_APWL + 18432*2)
#define WS_BNT  (WS_BNS + 1024)

__device__ __forceinline__ unsigned short f2bf(float f) {
  __hip_bfloat16 h = __float2bfloat16(f);
  return reinterpret_cast<unsigned short&>(h);
}
__device__ __forceinline__ float bfu2f(unsigned short u) {
  unsigned int v = ((unsigned int)u) << 16;
  return reinterpret_cast<float&>(v);
}

// ---- K0: BN fold + A-frag pre-swizzles ------------------------------------
// acw: [chunk20][mtile16][lane64][j8]; element = cw[m][c][k]
//   m = mtile*16+(lane&15), chunk = k*4+cc, c = cc*32+(lane>>4)*8+j
// apw: [chunk36][lane64][j8]; element = pw[m][c][tap] (0 for m>=10), hi/lo split
//   m = lane&15, tap = chunk>>2, c = (chunk&3)*32+(lane>>4)*8+j
__global__ __launch_bounds__(256) void k_pre(
    const float* __restrict__ cw, const float* __restrict__ pw,
    const float* __restrict__ gam, const float* __restrict__ bet,
    const float* __restrict__ mu, const float* __restrict__ var,
    unsigned short* __restrict__ acw, unsigned short* __restrict__ apwh,
    unsigned short* __restrict__ apwl,
    float* __restrict__ bns, float* __restrict__ bnt) {
  int i = blockIdx.x * 256 + threadIdx.x;          // 712*256 = 182272 = 163840+18432
  if (i < 163840) {
    int j = i & 7, lane = (i >> 3) & 63, mtile = (i >> 9) & 15;
    int cc = (i >> 13) & 3, k = i >> 15;
    int m = mtile * 16 + (lane & 15);
    int c = cc * 32 + (lane >> 4) * 8 + j;
    acw[i] = f2bf(cw[(m * C1 + c) * NP + k]);
  } else {
    int i2 = i - 163840;                           // 18432 elements
    int j = i2 & 7, lane = (i2 >> 3) & 63, chunk = i2 >> 9;
    int m = lane & 15, tap = chunk >> 2;
    int c = (chunk & 3) * 32 + (lane >> 4) * 8 + j;
    float wv = (m < 10) ? pw[(m * C1 + c) * 9 + tap] : 0.f;
    unsigned short hi = f2bf(wv);
    apwh[i2] = hi;
    apwl[i2] = f2bf(wv - bfu2f(hi));
  }
  if (blockIdx.x == 0) {
    int t = threadIdx.x;
    float s = gam[t] * rsqrtf(var[t] + 1e-5f);
    bns[t] = s;
    bnt[t] = bet[t] - mu[t] * s;
  }
}

// ---- K-T: transpose x fp32 NCHW -> channel-last double-bf16 (hi + lo) ------
__global__ __launch_bounds__(256) void k_trans(const float* __restrict__ x,
                                               unsigned short* __restrict__ xT,
                                               unsigned short* __restrict__ xTlo) {
  int t = threadIdx.x;
  int cq = t & 3, pl = t >> 2;                     // 4 channel-quads x 64 pixels
  int gp = blockIdx.x * 64 + pl;
  int b = gp / HW, p = gp - b * HW;
  const float* xp = x + (size_t)b * C1 * HW + p;
  unsigned short vh[32], vl[32];
#pragma unroll
  for (int i = 0; i < 32; ++i) {
    float f = xp[(size_t)(cq * 32 + i) * HW];
    unsigned short h = f2bf(f);
    vh[i] = h;
    vl[i] = f2bf(f - bfu2f(h));
  }
  uint4* dh = (uint4*)(xT + (size_t)gp * C1 + cq * 32);
  uint4* dl = (uint4*)(xTlo + (size_t)gp * C1 + cq * 32);
#pragma unroll
  for (int q = 0; q < 4; ++q) {
    dh[q] = *(uint4*)&vh[q * 8];
    dl[q] = *(uint4*)&vl[q * 8];
  }
}

// ---- K1: offset conv via double-bf16 MFMA + bilinear tables ----------------
// Wave handles 16 pixels; 36 chunks of K=32 (tap-major). No LDS in the loop.
__global__ __launch_bounds__(256) void k_offset(
    const unsigned short* __restrict__ xT, const unsigned short* __restrict__ xTlo,
    const unsigned short* __restrict__ apwh, const unsigned short* __restrict__ apwl,
    const float* __restrict__ pb,
    int4* __restrict__ idx4, float4* __restrict__ wgt4) {
  __shared__ float sOff[4][10][16];
  int t = threadIdx.x, wave = t >> 6, lane = t & 63;
  int n16 = lane & 15, koct = lane >> 4;
  int gp = blockIdx.x * 64 + wave * 16 + n16;
  int b = gp / HW, p = gp - b * HW;
  int h = p / 80, w = p - h * 80;
  const char* xTb = (const char*)xT + (size_t)b * HW * 256;
  const char* xTlb = (const char*)xTlo + (size_t)b * HW * 256;

  f32x4 acc = (f32x4)(0.f);
#pragma unroll
  for (int chunk = 0; chunk < 36; ++chunk) {
    int tap = chunk >> 2, cc = chunk & 3;
    int dh = tap / 3 - 1, dw = tap - (tap / 3) * 3 - 1;
    int hh = h + dh, ww = w + dw;
    bool ok = ((unsigned)hh < 80u) && ((unsigned)ww < 80u);
    short8 bh = 0, bl = 0;
    if (ok) {
      int boff = ((hh * 80 + ww) << 8) + cc * 64 + koct * 16;
      bh = *(const short8*)(xTb + boff);
      bl = *(const short8*)(xTlb + boff);
    }
    short8 ah = *(const short8*)(apwh + (chunk * 64 + lane) * 8);
    short8 al = *(const short8*)(apwl + (chunk * 64 + lane) * 8);
    acc = __builtin_amdgcn_mfma_f32_16x16x32_bf16(ah, bh, acc, 0, 0, 0);
    acc = __builtin_amdgcn_mfma_f32_16x16x32_bf16(ah, bl, acc, 0, 0, 0);
    acc = __builtin_amdgcn_mfma_f32_16x16x32_bf16(al, bh, acc, 0, 0, 0);
  }

  int quad = lane >> 4;
#pragma unroll
  for (int r = 0; r < 4; ++r) {
    int row = quad * 4 + r;
    if (row < 10) sOff[wave][row][n16] = acc[r];
  }
  __syncthreads();

  for (int task = t; task < 320; task += 256) {
    int wv = task / 80, rem = task - wv * 80, k = rem >> 4, n = rem & 15;
    int gp2 = blockIdx.x * 64 + wv * 16 + n;
    int b2 = gp2 / HW, p2 = gp2 - b2 * HW;
    int h2 = p2 / 80, w2 = p2 - h2 * 80;
    float px = sOff[wv][k][n] + pb[k] + (float)(h2 + (k >> 1));
    float py = sOff[wv][5 + k][n] + pb[5 + k] + (float)(w2 + (k & 1));
    float pf = floorf(px), qf = floorf(py);
    float x0 = fminf(fmaxf(pf, 0.f), 79.f);
    float x1 = fminf(fmaxf(pf + 1.f, 0.f), 79.f);
    float y0 = fminf(fmaxf(qf, 0.f), 79.f);
    float y1 = fminf(fmaxf(qf + 1.f, 0.f), 79.f);
    float pxc = fminf(fmaxf(px, 0.f), 79.f);
    float pyc = fminf(fmaxf(py, 0.f), 79.f);
    float wx0 = 1.f + (x0 - pxc), wx1 = 1.f - (x1 - pxc);
    float wy0 = 1.f + (y0 - pyc), wy1 = 1.f - (y1 - pyc);
    int ix0 = (int)x0, ix1 = (int)x1, iy0 = (int)y0, iy1 = (int)y1;
    int g = (b2 * NP + k) * HW + p2;
    idx4[g] = make_int4((ix0 * 80 + iy0) << 8, (ix1 * 80 + iy1) << 8,
                        (ix0 * 80 + iy1) << 8, (ix1 * 80 + iy0) << 8);
    wgt4[g] = make_float4(wx0 * wy0, wx1 * wy1, wx0 * wy1, wx1 * wy0);
  }
}

// ---- K3: fused gather + MFMA GEMM + BN + SiLU ------------------------------
#define PS 2080   // LDS plane stride (ushorts): 4160 B

__device__ __forceinline__ void stage_k(
    const char* xTb, const int4* sOffT, const float4* sWgtT,
    unsigned short* BsBuf, int k, int gn, int gcc) {
  int4   id = sOffT[k * 64 + gn];
  float4 wg = sWgtT[k * 64 + gn];
  int cb = gcc * 64;
#pragma unroll
  for (int s = 0; s < 4; ++s) {                    // 4 channel-octets
    union { uint4 v; unsigned short u[8]; } a0, a1, a2, a3, rr;
    a0.v = *(const uint4*)(xTb + id.x + cb + s * 16);
    a1.v = *(const uint4*)(xTb + id.y + cb + s * 16);
    a2.v = *(const uint4*)(xTb + id.z + cb + s * 16);
    a3.v = *(const uint4*)(xTb + id.w + cb + s * 16);
#pragma unroll
    for (int j = 0; j < 8; ++j) {
      float f = wg.x * bfu2f(a0.u[j]) + wg.y * bfu2f(a1.u[j])
              + wg.z * bfu2f(a2.u[j]) + wg.w * bfu2f(a3.u[j]);
      rr.u[j] = f2bf(f);
    }
    *(uint4*)&BsBuf[gcc * PS + (((gn >> 4) * 64) + s * 16 + (gn & 15)) * 8] = rr.v;
  }
}

__global__ __launch_bounds__(256) void k_main(
    const unsigned short* __restrict__ xT,
    const unsigned short* __restrict__ acw,
    const int4* __restrict__ idx4, const float4* __restrict__ wgt4,
    const float* __restrict__ bns, const float* __restrict__ bnt,
    float* __restrict__ out) {
  __shared__ unsigned short Bs[2][4 * PS];
  __shared__ int4   sOffT[NP * 64];
  __shared__ float4 sWgtT[NP * 64];

  int t = threadIdx.x;
  int gp0 = blockIdx.x * 64;
  int b = gp0 / HW, pbase = gp0 - b * HW;

  for (int i = t; i < NP * 64; i += 256) {
    int k = i >> 6, n = i & 63;
    int g = (b * NP + k) * HW + pbase + n;
    sOffT[i] = idx4[g];
    sWgtT[i] = wgt4[g];
  }

  int wave = t >> 6, lane = t & 63;
  int gn = t >> 2, gcc = t & 3;
  const char* xTb = (const char*)xT + (size_t)b * HW * 256;

  f32x4 acc[4][4];
#pragma unroll
  for (int mt = 0; mt < 4; ++mt)
#pragma unroll
    for (int nt = 0; nt < 4; ++nt) acc[mt][nt] = (f32x4)(0.f);

  __syncthreads();                      // tables staged
  stage_k(xTb, sOffT, sWgtT, Bs[0], 0, gn, gcc);

  for (int k = 0; k < NP; ++k) {
    __syncthreads();                    // buf[k&1] ready for all waves
    const unsigned short* Bk = Bs[k & 1];
#pragma unroll
    for (int cc = 0; cc < 4; ++cc) {
      short8 bfr[4];
#pragma unroll
      for (int nt = 0; nt < 4; ++nt)
        bfr[nt] = *(const short8*)&Bk[cc * PS + (nt * 64 + lane) * 8];
      const unsigned short* ab =
          acw + (size_t)((((k * 4 + cc) * 16) + wave * 4) * 64 + lane) * 8;
#pragma unroll
      for (int mt = 0; mt < 4; ++mt) {
        short8 a = *(const short8*)(ab + mt * 64 * 8);
#pragma unroll
        for (int nt = 0; nt < 4; ++nt)
          acc[mt][nt] = __builtin_amdgcn_mfma_f32_16x16x32_bf16(
              a, bfr[nt], acc[mt][nt], 0, 0, 0);
      }
    }
    if (k < NP - 1)
      stage_k(xTb, sOffT, sWgtT, Bs[(k + 1) & 1], k + 1, gn, gcc);
  }

  // ---- epilogue: BN + SiLU
  int quad = lane >> 4, col = lane & 15;
#pragma unroll
  for (int mt = 0; mt < 4; ++mt) {
    int m0 = wave * 64 + mt * 16 + quad * 4;
#pragma unroll
    for (int r = 0; r < 4; ++r) {
      int m = m0 + r;
      float s = bns[m], sh = bnt[m];
      float* op = out + ((size_t)(b * C2 + m)) * HW + pbase;
#pragma unroll
      for (int nt = 0; nt < 4; ++nt) {
        float y = fmaf(acc[mt][nt][r], s, sh);
        op[nt * 16 + col] = y * (1.f / (1.f + __expf(-y)));
      }
    }
  }
}

extern "C" void kernel_launch(void* const* d_in, const int* in_sizes, int n_in,
                              void* d_out, int out_size, void* d_ws, size_t ws_size,
                              hipStream_t stream) {
  const float* x  = (const float*)d_in[0];
  const float* pw = (const float*)d_in[1];
  const float* pb = (const float*)d_in[2];
  const float* cw = (const float*)d_in[3];
  const float* bg = (const float*)d_in[4];
  const float* bb = (const float*)d_in[5];
  const float* bm = (const float*)d_in[6];
  const float* bv = (const float*)d_in[7];
  float* out = (float*)d_out;

  char* ws = (char*)d_ws;
  int4*           idx4 = (int4*)(ws + WS_IDX4);
  float4*         wgt4 = (float4*)(ws + WS_WGT4);
  unsigned short* xT   = (unsigned short*)(ws + WS_XT);
  unsigned short* xTlo = (unsigned short*)(ws + WS_XTLO);
  unsigned short* acw  = (unsigned short*)(ws + WS_ACW);
  unsigned short* apwh = (unsigned short*)(ws + WS_APWH);
  unsigned short* apwl = (unsigned short*)(ws + WS_APWL);
  float*          bns  = (float*)(ws + WS_BNS);
  float*          bnt  = (float*)(ws + WS_BNT);

  k_pre<<<712, 256, 0, stream>>>(cw, pw, bg, bb, bm, bv, acw, apwh, apwl, bns, bnt);
  k_trans<<<800, 256, 0, stream>>>(x, xT, xTlo);
  k_offset<<<800, 256, 0, stream>>>(xT, xTlo, apwh, apwl, pb, idx4, wgt4);
  k_main<<<800, 256, 0, stream>>>(xT, acw, idx4, wgt4, bns, bnt, out);
}

// Round 6
// 208.332 us; speedup vs baseline: 2.9665x; 1.1004x over previous
//
#include <hip/hip_runtime.h>
#include <hip/hip_bf16.h>

// AKConv fp32 in/out, bf16 MFMA everywhere.
//  k_pre   : BN fold + A-frag pre-swizzles: cw->acw (bf16), pw->apw hi/lo (double-bf16)
//  k_trans : x[b][c][hw] fp32 -> xT (bf16 hi) + xTlo (bf16 residual), channel-last
//  k_offset: 3x3 offset conv as double-bf16 MFMA GEMM + bilinear tables
//  k_main  : fused gather + MFMA GEMM (M=256,K=640,N=51200) + BN + SiLU, dbuf.
//            Gather lane map: (px=lane&15, j=lane>>4) -> 4 lanes share each 64B line
//            (one L1 lookup per needed line); LDS staging is identity/coalesced.

typedef __attribute__((ext_vector_type(8))) short short8;
typedef __attribute__((ext_vector_type(4))) float f32x4;

#define Bsz 8
#define C1 128
#define C2 256
#define HW 6400
#define NP 5

// ---- workspace layout (bytes) ----
#define NPOS (Bsz*NP*HW)                    // 256000 samples
#define WS_IDX4 0                           // int4[NPOS]: corner BYTE offsets into xT image
#define WS_WGT4 (WS_IDX4 + NPOS*16)         // float4[NPOS]
#define WS_XT   (WS_WGT4 + NPOS*16)         // ushort xT[8][6400][128]   13.1 MB (hi)
#define WS_XTLO (WS_XT + Bsz*HW*C1*2)       // ushort xTlo[8][6400][128] 13.1 MB (residual)
#define WS_ACW  (WS_XTLO + Bsz*HW*C1*2)     // ushort acw[163840]  (cw A-frags)
#define WS_APWH (WS_ACW + C2*C1*NP*2)       // ushort apw_hi[18432]
#define WS_APWL (WS_APWH + 18432*2)         // ushort apw_lo[18432]
#define WS_BNS  (WS_APWL + 18432*2)
#define WS_BNT  (WS_BNS + 1024)

__device__ __forceinline__ unsigned short f2bf(float f) {
  __hip_bfloat16 h = __float2bfloat16(f);
  return reinterpret_cast<unsigned short&>(h);
}
__device__ __forceinline__ float bfu2f(unsigned short u) {
  unsigned int v = ((unsigned int)u) << 16;
  return reinterpret_cast<float&>(v);
}

// ---- K0: BN fold + A-frag pre-swizzles ------------------------------------
__global__ __launch_bounds__(256) void k_pre(
    const float* __restrict__ cw, const float* __restrict__ pw,
    const float* __restrict__ gam, const float* __restrict__ bet,
    const float* __restrict__ mu, const float* __restrict__ var,
    unsigned short* __restrict__ acw, unsigned short* __restrict__ apwh,
    unsigned short* __restrict__ apwl,
    float* __restrict__ bns, float* __restrict__ bnt) {
  int i = blockIdx.x * 256 + threadIdx.x;          // 712*256 = 182272 = 163840+18432
  if (i < 163840) {
    int j = i & 7, lane = (i >> 3) & 63, mtile = (i >> 9) & 15;
    int cc = (i >> 13) & 3, k = i >> 15;
    int m = mtile * 16 + (lane & 15);
    int c = cc * 32 + (lane >> 4) * 8 + j;
    acw[i] = f2bf(cw[(m * C1 + c) * NP + k]);
  } else {
    int i2 = i - 163840;                           // 18432 elements
    int j = i2 & 7, lane = (i2 >> 3) & 63, chunk = i2 >> 9;
    int m = lane & 15, tap = chunk >> 2;
    int c = (chunk & 3) * 32 + (lane >> 4) * 8 + j;
    float wv = (m < 10) ? pw[(m * C1 + c) * 9 + tap] : 0.f;
    unsigned short hi = f2bf(wv);
    apwh[i2] = hi;
    apwl[i2] = f2bf(wv - bfu2f(hi));
  }
  if (blockIdx.x == 0) {
    int t = threadIdx.x;
    float s = gam[t] * rsqrtf(var[t] + 1e-5f);
    bns[t] = s;
    bnt[t] = bet[t] - mu[t] * s;
  }
}

// ---- K-T: transpose x fp32 NCHW -> channel-last double-bf16 (hi + lo) ------
__global__ __launch_bounds__(256) void k_trans(const float* __restrict__ x,
                                               unsigned short* __restrict__ xT,
                                               unsigned short* __restrict__ xTlo) {
  int t = threadIdx.x;
  int cq = t & 3, pl = t >> 2;                     // 4 channel-quads x 64 pixels
  int gp = blockIdx.x * 64 + pl;
  int b = gp / HW, p = gp - b * HW;
  const float* xp = x + (size_t)b * C1 * HW + p;
  unsigned short vh[32], vl[32];
#pragma unroll
  for (int i = 0; i < 32; ++i) {
    float f = xp[(size_t)(cq * 32 + i) * HW];
    unsigned short h = f2bf(f);
    vh[i] = h;
    vl[i] = f2bf(f - bfu2f(h));
  }
  uint4* dh = (uint4*)(xT + (size_t)gp * C1 + cq * 32);
  uint4* dl = (uint4*)(xTlo + (size_t)gp * C1 + cq * 32);
#pragma unroll
  for (int q = 0; q < 4; ++q) {
    dh[q] = *(uint4*)&vh[q * 8];
    dl[q] = *(uint4*)&vl[q * 8];
  }
}

// ---- K1: offset conv via double-bf16 MFMA + bilinear tables ----------------
__global__ __launch_bounds__(256) void k_offset(
    const unsigned short* __restrict__ xT, const unsigned short* __restrict__ xTlo,
    const unsigned short* __restrict__ apwh, const unsigned short* __restrict__ apwl,
    const float* __restrict__ pb,
    int4* __restrict__ idx4, float4* __restrict__ wgt4) {
  __shared__ float sOff[4][10][16];
  int t = threadIdx.x, wave = t >> 6, lane = t & 63;
  int n16 = lane & 15, koct = lane >> 4;
  int gp = blockIdx.x * 64 + wave * 16 + n16;
  int b = gp / HW, p = gp - b * HW;
  int h = p / 80, w = p - h * 80;
  const char* xTb = (const char*)xT + (size_t)b * HW * 256;
  const char* xTlb = (const char*)xTlo + (size_t)b * HW * 256;

  f32x4 acc = (f32x4)(0.f);
#pragma unroll
  for (int chunk = 0; chunk < 36; ++chunk) {
    int tap = chunk >> 2, cc = chunk & 3;
    int dh = tap / 3 - 1, dw = tap - (tap / 3) * 3 - 1;
    int hh = h + dh, ww = w + dw;
    bool ok = ((unsigned)hh < 80u) && ((unsigned)ww < 80u);
    short8 bh = 0, bl = 0;
    if (ok) {
      int boff = ((hh * 80 + ww) << 8) + cc * 64 + koct * 16;
      bh = *(const short8*)(xTb + boff);
      bl = *(const short8*)(xTlb + boff);
    }
    short8 ah = *(const short8*)(apwh + (chunk * 64 + lane) * 8);
    short8 al = *(const short8*)(apwl + (chunk * 64 + lane) * 8);
    acc = __builtin_amdgcn_mfma_f32_16x16x32_bf16(ah, bh, acc, 0, 0, 0);
    acc = __builtin_amdgcn_mfma_f32_16x16x32_bf16(ah, bl, acc, 0, 0, 0);
    acc = __builtin_amdgcn_mfma_f32_16x16x32_bf16(al, bh, acc, 0, 0, 0);
  }

  int quad = lane >> 4;
#pragma unroll
  for (int r = 0; r < 4; ++r) {
    int row = quad * 4 + r;
    if (row < 10) sOff[wave][row][n16] = acc[r];
  }
  __syncthreads();

  for (int task = t; task < 320; task += 256) {
    int wv = task / 80, rem = task - wv * 80, k = rem >> 4, n = rem & 15;
    int gp2 = blockIdx.x * 64 + wv * 16 + n;
    int b2 = gp2 / HW, p2 = gp2 - b2 * HW;
    int h2 = p2 / 80, w2 = p2 - h2 * 80;
    float px = sOff[wv][k][n] + pb[k] + (float)(h2 + (k >> 1));
    float py = sOff[wv][5 + k][n] + pb[5 + k] + (float)(w2 + (k & 1));
    float pf = floorf(px), qf = floorf(py);
    float x0 = fminf(fmaxf(pf, 0.f), 79.f);
    float x1 = fminf(fmaxf(pf + 1.f, 0.f), 79.f);
    float y0 = fminf(fmaxf(qf, 0.f), 79.f);
    float y1 = fminf(fmaxf(qf + 1.f, 0.f), 79.f);
    float pxc = fminf(fmaxf(px, 0.f), 79.f);
    float pyc = fminf(fmaxf(py, 0.f), 79.f);
    float wx0 = 1.f + (x0 - pxc), wx1 = 1.f - (x1 - pxc);
    float wy0 = 1.f + (y0 - pyc), wy1 = 1.f - (y1 - pyc);
    int ix0 = (int)x0, ix1 = (int)x1, iy0 = (int)y0, iy1 = (int)y1;
    int g = (b2 * NP + k) * HW + p2;
    idx4[g] = make_int4((ix0 * 80 + iy0) << 8, (ix1 * 80 + iy1) << 8,
                        (ix0 * 80 + iy1) << 8, (ix1 * 80 + iy0) << 8);
    wgt4[g] = make_float4(wx0 * wy0, wx1 * wy1, wx0 * wy1, wx1 * wy0);
  }
}

// ---- K3: fused gather + MFMA GEMM + BN + SiLU ------------------------------
// Bs unit u (16B) of plane (cc, grp): octet j of pixel grp*16+p4 at u = j*16+p4.
// Staging lane (p4=lane&15, j=lane>>4) writes unit==lane; compute lane
// (n16=lane&15, ko=lane>>4) reads unit==lane. Both sides contiguous 1 KB/wave.
__device__ __forceinline__ void stage_k(
    const char* xTb, const int4* __restrict__ idx4, const float4* __restrict__ wgt4,
    unsigned short* BsBuf, size_t sampBase, int k, int grp, int lane) {
  int p4 = lane & 15, j = lane >> 4;
  size_t g = sampBase + (size_t)k * HW + grp * 16 + p4;
  int4   id = idx4[g];
  float4 wg = wgt4[g];
  int cj = j * 16;
#pragma unroll
  for (int cc = 0; cc < 4; ++cc) {
    int cb = cc * 64 + cj;
    union { uint4 v; unsigned short u[8]; } a0, a1, a2, a3, rr;
    a0.v = *(const uint4*)(xTb + id.x + cb);
    a1.v = *(const uint4*)(xTb + id.y + cb);
    a2.v = *(const uint4*)(xTb + id.z + cb);
    a3.v = *(const uint4*)(xTb + id.w + cb);
#pragma unroll
    for (int e = 0; e < 8; ++e) {
      float f = wg.x * bfu2f(a0.u[e]) + wg.y * bfu2f(a1.u[e])
              + wg.z * bfu2f(a2.u[e]) + wg.w * bfu2f(a3.u[e]);
      rr.u[e] = f2bf(f);
    }
    *(uint4*)&BsBuf[((cc * 4 + grp) * 64 + lane) * 8] = rr.v;
  }
}

__global__ __launch_bounds__(256) void k_main(
    const unsigned short* __restrict__ xT,
    const unsigned short* __restrict__ acw,
    const int4* __restrict__ idx4, const float4* __restrict__ wgt4,
    const float* __restrict__ bns, const float* __restrict__ bnt,
    float* __restrict__ out) {
  __shared__ unsigned short Bs[2][16 * 64 * 8];    // 2 x 16 KB

  int t = threadIdx.x;
  int gp0 = blockIdx.x * 64;
  int b = gp0 / HW, pbase = gp0 - b * HW;
  int wave = t >> 6, lane = t & 63;
  const char* xTb = (const char*)xT + (size_t)b * HW * 256;
  size_t sampBase = (size_t)b * NP * HW + pbase;

  f32x4 acc[4][4];
#pragma unroll
  for (int mt = 0; mt < 4; ++mt)
#pragma unroll
    for (int nt = 0; nt < 4; ++nt) acc[mt][nt] = (f32x4)(0.f);

  stage_k(xTb, idx4, wgt4, Bs[0], sampBase, 0, wave, lane);

  for (int k = 0; k < NP; ++k) {
    __syncthreads();                    // buf[k&1] ready for all waves
    const unsigned short* Bk = Bs[k & 1];
#pragma unroll
    for (int cc = 0; cc < 4; ++cc) {
      short8 bfr[4];
#pragma unroll
      for (int nt = 0; nt < 4; ++nt)
        bfr[nt] = *(const short8*)&Bk[((cc * 4 + nt) * 64 + lane) * 8];
      const unsigned short* ab =
          acw + (size_t)((((k * 4 + cc) * 16) + wave * 4) * 64 + lane) * 8;
#pragma unroll
      for (int mt = 0; mt < 4; ++mt) {
        short8 a = *(const short8*)(ab + mt * 64 * 8);
#pragma unroll
        for (int nt = 0; nt < 4; ++nt)
          acc[mt][nt] = __builtin_amdgcn_mfma_f32_16x16x32_bf16(
              a, bfr[nt], acc[mt][nt], 0, 0, 0);
      }
    }
    if (k < NP - 1)
      stage_k(xTb, idx4, wgt4, Bs[(k + 1) & 1], sampBase, k + 1, wave, lane);
  }

  // ---- epilogue: BN + SiLU
  int quad = lane >> 4, col = lane & 15;
#pragma unroll
  for (int mt = 0; mt < 4; ++mt) {
    int m0 = wave * 64 + mt * 16 + quad * 4;
#pragma unroll
    for (int r = 0; r < 4; ++r) {
      int m = m0 + r;
      float s = bns[m], sh = bnt[m];
      float* op = out + ((size_t)(b * C2 + m)) * HW + pbase;
#pragma unroll
      for (int nt = 0; nt < 4; ++nt) {
        float y = fmaf(acc[mt][nt][r], s, sh);
        op[nt * 16 + col] = y * (1.f / (1.f + __expf(-y)));
      }
    }
  }
}

extern "C" void kernel_launch(void* const* d_in, const int* in_sizes, int n_in,
                              void* d_out, int out_size, void* d_ws, size_t ws_size,
                              hipStream_t stream) {
  const float* x  = (const float*)d_in[0];
  const float* pw = (const float*)d_in[1];
  const float* pb = (const float*)d_in[2];
  const float* cw = (const float*)d_in[3];
  const float* bg = (const float*)d_in[4];
  const float* bb = (const float*)d_in[5];
  const float* bm = (const float*)d_in[6];
  const float* bv = (const float*)d_in[7];
  float* out = (float*)d_out;

  char* ws = (char*)d_ws;
  int4*           idx4 = (int4*)(ws + WS_IDX4);
  float4*         wgt4 = (float4*)(ws + WS_WGT4);
  unsigned short* xT   = (unsigned short*)(ws + WS_XT);
  unsigned short* xTlo = (unsigned short*)(ws + WS_XTLO);
  unsigned short* acw  = (unsigned short*)(ws + WS_ACW);
  unsigned short* apwh = (unsigned short*)(ws + WS_APWH);
  unsigned short* apwl = (unsigned short*)(ws + WS_APWL);
  float*          bns  = (float*)(ws + WS_BNS);
  float*          bnt  = (float*)(ws + WS_BNT);

  k_pre<<<712, 256, 0, stream>>>(cw, pw, bg, bb, bm, bv, acw, apwh, apwl, bns, bnt);
  k_trans<<<800, 256, 0, stream>>>(x, xT, xTlo);
  k_offset<<<800, 256, 0, stream>>>(xT, xTlo, apwh, apwl, pb, idx4, wgt4);
  k_main<<<800, 256, 0, stream>>>(xT, acw, idx4, wgt4, bns, bnt, out);
}

// Round 7
// 197.970 us; speedup vs baseline: 3.1218x; 1.0523x over previous
//
#include <hip/hip_runtime.h>
#include <hip/hip_bf16.h>

// AKConv fp32 in/out, bf16 MFMA everywhere.
//  k_pre   : BN fold + A-frag pre-swizzles: cw->acw (bf16), pw->apw hi/lo (double-bf16)
//  k_trans : x[b][c][hw] fp32 -> xT (bf16 hi) + xTlo (bf16 residual), channel-last,
//            LDS-transpose, coalesced both sides
//  k_offset: 3x3 offset conv as double-bf16 MFMA GEMM + bilinear tables (1 wave/block)
//  k_main  : fused gather + MFMA GEMM (M=256,K=640,N=51200) + BN + SiLU.
//            N=32 tiles (1600 blocks); gather loads issued BEFORE compute(k) so
//            L2 latency hides behind the MFMA stream; dbuf, fully unrolled k.

typedef __attribute__((ext_vector_type(8))) short short8;
typedef __attribute__((ext_vector_type(4))) float f32x4;

#define Bsz 8
#define C1 128
#define C2 256
#define HW 6400
#define NP 5

// ---- workspace layout (bytes) ----
#define NPOS (Bsz*NP*HW)                    // 256000 samples
#define WS_IDX4 0                           // int4[NPOS]: corner BYTE offsets into xT image
#define WS_WGT4 (WS_IDX4 + NPOS*16)         // float4[NPOS]
#define WS_XT   (WS_WGT4 + NPOS*16)         // ushort xT[8][6400][128]   13.1 MB (hi)
#define WS_XTLO (WS_XT + Bsz*HW*C1*2)       // ushort xTlo[8][6400][128] 13.1 MB (residual)
#define WS_ACW  (WS_XTLO + Bsz*HW*C1*2)     // ushort acw[163840]  (cw A-frags)
#define WS_APWH (WS_ACW + C2*C1*NP*2)       // ushort apw_hi[18432]
#define WS_APWL (WS_APWH + 18432*2)         // ushort apw_lo[18432]
#define WS_BNS  (WS_APWL + 18432*2)
#define WS_BNT  (WS_BNS + 1024)

__device__ __forceinline__ unsigned short f2bf(float f) {
  __hip_bfloat16 h = __float2bfloat16(f);
  return reinterpret_cast<unsigned short&>(h);
}
__device__ __forceinline__ float bfu2f(unsigned short u) {
  unsigned int v = ((unsigned int)u) << 16;
  return reinterpret_cast<float&>(v);
}

// ---- K0: BN fold + A-frag pre-swizzles ------------------------------------
__global__ __launch_bounds__(256) void k_pre(
    const float* __restrict__ cw, const float* __restrict__ pw,
    const float* __restrict__ gam, const float* __restrict__ bet,
    const float* __restrict__ mu, const float* __restrict__ var,
    unsigned short* __restrict__ acw, unsigned short* __restrict__ apwh,
    unsigned short* __restrict__ apwl,
    float* __restrict__ bns, float* __restrict__ bnt) {
  int i = blockIdx.x * 256 + threadIdx.x;          // 712*256 = 182272 = 163840+18432
  if (i < 163840) {
    int j = i & 7, lane = (i >> 3) & 63, mtile = (i >> 9) & 15;
    int cc = (i >> 13) & 3, k = i >> 15;
    int m = mtile * 16 + (lane & 15);
    int c = cc * 32 + (lane >> 4) * 8 + j;
    acw[i] = f2bf(cw[(m * C1 + c) * NP + k]);
  } else {
    int i2 = i - 163840;                           // 18432 elements
    int j = i2 & 7, lane = (i2 >> 3) & 63, chunk = i2 >> 9;
    int m = lane & 15, tap = chunk >> 2;
    int c = (chunk & 3) * 32 + (lane >> 4) * 8 + j;
    float wv = (m < 10) ? pw[(m * C1 + c) * 9 + tap] : 0.f;
    unsigned short hi = f2bf(wv);
    apwh[i2] = hi;
    apwl[i2] = f2bf(wv - bfu2f(hi));
  }
  if (blockIdx.x == 0) {
    int t = threadIdx.x;
    float s = gam[t] * rsqrtf(var[t] + 1e-5f);
    bns[t] = s;
    bnt[t] = bet[t] - mu[t] * s;
  }
}

// ---- K-T: LDS-transpose x fp32 NCHW -> channel-last double-bf16 (hi+lo) ----
// Block: 128 channels x 32 pixels. Reads float4 along pixels (coalesced);
// writes 16B units along channels (coalesced). 1600 blocks.
__global__ __launch_bounds__(256) void k_trans(const float* __restrict__ x,
                                               unsigned short* __restrict__ xT,
                                               unsigned short* __restrict__ xTlo) {
  __shared__ float lds[128][33];
  int t = threadIdx.x;
  int gp0 = blockIdx.x * 32;
  int b = gp0 / HW, p0 = gp0 - b * HW;
  const float* xb = x + (size_t)b * C1 * HW;
  int q = t & 7, r = t >> 3;                       // q: px-quad, r: channel 0..31
#pragma unroll
  for (int pass = 0; pass < 4; ++pass) {
    int c = pass * 32 + r;
    float4 v = *(const float4*)(xb + (size_t)c * HW + p0 + q * 4);
    lds[c][q * 4 + 0] = v.x;
    lds[c][q * 4 + 1] = v.y;
    lds[c][q * 4 + 2] = v.z;
    lds[c][q * 4 + 3] = v.w;
  }
  __syncthreads();
  int px = t >> 3, u = t & 7;                      // px 0..31, unit 0..7
#pragma unroll
  for (int it = 0; it < 2; ++it) {
    int unit = it * 8 + u;
    int c0 = unit * 8;
    unsigned short vh[8], vl[8];
#pragma unroll
    for (int e = 0; e < 8; ++e) {
      float f = lds[c0 + e][px];
      unsigned short h = f2bf(f);
      vh[e] = h;
      vl[e] = f2bf(f - bfu2f(h));
    }
    size_t base = (size_t)(gp0 + px) * C1 + unit * 8;
    *(uint4*)(xT + base) = *(uint4*)vh;
    *(uint4*)(xTlo + base) = *(uint4*)vl;
  }
}

// ---- K1: offset conv via double-bf16 MFMA + bilinear tables ----------------
// One wave per block, 16 pixels per wave, grid 3200.
__global__ __launch_bounds__(64) void k_offset(
    const unsigned short* __restrict__ xT, const unsigned short* __restrict__ xTlo,
    const unsigned short* __restrict__ apwh, const unsigned short* __restrict__ apwl,
    const float* __restrict__ pb,
    int4* __restrict__ idx4, float4* __restrict__ wgt4) {
  __shared__ float sOff[10][16];
  int t = threadIdx.x, lane = t;
  int n16 = lane & 15, koct = lane >> 4;
  int gp = blockIdx.x * 16 + n16;
  int b = gp / HW, p = gp - b * HW;
  int h = p / 80, w = p - h * 80;
  const char* xTb = (const char*)xT + (size_t)b * HW * 256;
  const char* xTlb = (const char*)xTlo + (size_t)b * HW * 256;

  f32x4 acc = (f32x4)(0.f);
#pragma unroll
  for (int chunk = 0; chunk < 36; ++chunk) {
    int tap = chunk >> 2, cc = chunk & 3;
    int dh = tap / 3 - 1, dw = tap - (tap / 3) * 3 - 1;
    int hh = h + dh, ww = w + dw;
    bool ok = ((unsigned)hh < 80u) && ((unsigned)ww < 80u);
    short8 bh = 0, bl = 0;
    if (ok) {
      int boff = ((hh * 80 + ww) << 8) + cc * 64 + koct * 16;
      bh = *(const short8*)(xTb + boff);
      bl = *(const short8*)(xTlb + boff);
    }
    short8 ah = *(const short8*)(apwh + (chunk * 64 + lane) * 8);
    short8 al = *(const short8*)(apwl + (chunk * 64 + lane) * 8);
    acc = __builtin_amdgcn_mfma_f32_16x16x32_bf16(ah, bh, acc, 0, 0, 0);
    acc = __builtin_amdgcn_mfma_f32_16x16x32_bf16(ah, bl, acc, 0, 0, 0);
    acc = __builtin_amdgcn_mfma_f32_16x16x32_bf16(al, bh, acc, 0, 0, 0);
  }

  int quad = lane >> 4;
#pragma unroll
  for (int r = 0; r < 4; ++r) {
    int row = quad * 4 + r;
    if (row < 10) sOff[row][n16] = acc[r];
  }
  __syncthreads();

  for (int task = t; task < 80; task += 64) {
    int k = task >> 4, n = task & 15;
    int gp2 = blockIdx.x * 16 + n;
    int b2 = gp2 / HW, p2 = gp2 - b2 * HW;
    int h2 = p2 / 80, w2 = p2 - h2 * 80;
    float px = sOff[k][n] + pb[k] + (float)(h2 + (k >> 1));
    float py = sOff[5 + k][n] + pb[5 + k] + (float)(w2 + (k & 1));
    float pf = floorf(px), qf = floorf(py);
    float x0 = fminf(fmaxf(pf, 0.f), 79.f);
    float x1 = fminf(fmaxf(pf + 1.f, 0.f), 79.f);
    float y0 = fminf(fmaxf(qf, 0.f), 79.f);
    float y1 = fminf(fmaxf(qf + 1.f, 0.f), 79.f);
    float pxc = fminf(fmaxf(px, 0.f), 79.f);
    float pyc = fminf(fmaxf(py, 0.f), 79.f);
    float wx0 = 1.f + (x0 - pxc), wx1 = 1.f - (x1 - pxc);
    float wy0 = 1.f + (y0 - pyc), wy1 = 1.f - (y1 - pyc);
    int ix0 = (int)x0, ix1 = (int)x1, iy0 = (int)y0, iy1 = (int)y1;
    int g = (b2 * NP + k) * HW + p2;
    idx4[g] = make_int4((ix0 * 80 + iy0) << 8, (ix1 * 80 + iy1) << 8,
                        (ix0 * 80 + iy1) << 8, (ix1 * 80 + iy0) << 8);
    wgt4[g] = make_float4(wx0 * wy0, wx1 * wy1, wx0 * wy1, wx1 * wy0);
  }
}

// ---- K3: fused gather + MFMA GEMM + BN + SiLU ------------------------------
// Block: M=256, N=32 px; 1600 blocks; 4 waves. Wave w stages (grp=w&1,
// cchalf=w>>1): per lane 2cc x 4 corner loads of 16B, 4 j-lanes share each
// 64B line. Loads issue before compute(k); weighted-sum + ds_write after.
__device__ __forceinline__ void stage_load(
    const char* xTb, const int4* __restrict__ idx4, const float4* __restrict__ wgt4,
    size_t sampBase, int k, int grp, int cchalf, int lane,
    uint4 q[2][4], float4& wg) {
  int p4 = lane & 15, j = lane >> 4;
  size_t g = sampBase + (size_t)k * HW + grp * 16 + p4;
  int4 id = idx4[g];
  wg = wgt4[g];
  int cj = j * 16;
#pragma unroll
  for (int hf = 0; hf < 2; ++hf) {
    int cb = (cchalf * 2 + hf) * 64 + cj;
    q[hf][0] = *(const uint4*)(xTb + id.x + cb);
    q[hf][1] = *(const uint4*)(xTb + id.y + cb);
    q[hf][2] = *(const uint4*)(xTb + id.z + cb);
    q[hf][3] = *(const uint4*)(xTb + id.w + cb);
  }
}

__device__ __forceinline__ void stage_store(
    unsigned short* BsBuf, int grp, int cchalf, int lane,
    uint4 q[2][4], float4 wg) {
#pragma unroll
  for (int hf = 0; hf < 2; ++hf) {
    int cc = cchalf * 2 + hf;
    const unsigned short* a0 = (const unsigned short*)&q[hf][0];
    const unsigned short* a1 = (const unsigned short*)&q[hf][1];
    const unsigned short* a2 = (const unsigned short*)&q[hf][2];
    const unsigned short* a3 = (const unsigned short*)&q[hf][3];
    union { uint4 v; unsigned short u[8]; } rr;
#pragma unroll
    for (int e = 0; e < 8; ++e) {
      float f = wg.x * bfu2f(a0[e]) + wg.y * bfu2f(a1[e])
              + wg.z * bfu2f(a2[e]) + wg.w * bfu2f(a3[e]);
      rr.u[e] = f2bf(f);
    }
    *(uint4*)&BsBuf[((cc * 2 + grp) * 64 + lane) * 8] = rr.v;
  }
}

__global__ __launch_bounds__(256) void k_main(
    const unsigned short* __restrict__ xT,
    const unsigned short* __restrict__ acw,
    const int4* __restrict__ idx4, const float4* __restrict__ wgt4,
    const float* __restrict__ bns, const float* __restrict__ bnt,
    float* __restrict__ out) {
  __shared__ unsigned short Bs[2][8 * 64 * 8];     // 2 x 8 KB

  int t = threadIdx.x;
  int gp0 = blockIdx.x * 32;
  int b = gp0 / HW, pbase = gp0 - b * HW;
  int wave = t >> 6, lane = t & 63;
  int grp = wave & 1, cchalf = wave >> 1;
  const char* xTb = (const char*)xT + (size_t)b * HW * 256;
  size_t sampBase = (size_t)b * NP * HW + pbase;

  f32x4 acc[4][2];
#pragma unroll
  for (int mt = 0; mt < 4; ++mt)
#pragma unroll
    for (int nt = 0; nt < 2; ++nt) acc[mt][nt] = (f32x4)(0.f);

  uint4 pf[2][4];
  float4 pwg;
  stage_load(xTb, idx4, wgt4, sampBase, 0, grp, cchalf, lane, pf, pwg);
  stage_store(Bs[0], grp, cchalf, lane, pf, pwg);

#pragma unroll
  for (int k = 0; k < NP; ++k) {
    __syncthreads();                    // Bs[k&1] staged for all waves
    if (k + 1 < NP)
      stage_load(xTb, idx4, wgt4, sampBase, k + 1, grp, cchalf, lane, pf, pwg);
    const unsigned short* Bk = Bs[k & 1];
#pragma unroll
    for (int cc = 0; cc < 4; ++cc) {
      short8 bfr[2];
#pragma unroll
      for (int nt = 0; nt < 2; ++nt)
        bfr[nt] = *(const short8*)&Bk[((cc * 2 + nt) * 64 + lane) * 8];
      const unsigned short* ab =
          acw + (size_t)((((k * 4 + cc) * 16) + wave * 4) * 64 + lane) * 8;
#pragma unroll
      for (int mt = 0; mt < 4; ++mt) {
        short8 a = *(const short8*)(ab + mt * 64 * 8);
#pragma unroll
        for (int nt = 0; nt < 2; ++nt)
          acc[mt][nt] = __builtin_amdgcn_mfma_f32_16x16x32_bf16(
              a, bfr[nt], acc[mt][nt], 0, 0, 0);
      }
    }
    if (k + 1 < NP)
      stage_store(Bs[(k + 1) & 1], grp, cchalf, lane, pf, pwg);
  }

  // ---- epilogue: BN + SiLU
  int quad = lane >> 4, col = lane & 15;
#pragma unroll
  for (int mt = 0; mt < 4; ++mt) {
    int m0 = wave * 64 + mt * 16 + quad * 4;
#pragma unroll
    for (int r = 0; r < 4; ++r) {
      int m = m0 + r;
      float s = bns[m], sh = bnt[m];
      float* op = out + ((size_t)(b * C2 + m)) * HW + pbase;
#pragma unroll
      for (int nt = 0; nt < 2; ++nt) {
        float y = fmaf(acc[mt][nt][r], s, sh);
        op[nt * 16 + col] = y * (1.f / (1.f + __expf(-y)));
      }
    }
  }
}

extern "C" void kernel_launch(void* const* d_in, const int* in_sizes, int n_in,
                              void* d_out, int out_size, void* d_ws, size_t ws_size,
                              hipStream_t stream) {
  const float* x  = (const float*)d_in[0];
  const float* pw = (const float*)d_in[1];
  const float* pb = (const float*)d_in[2];
  const float* cw = (const float*)d_in[3];
  const float* bg = (const float*)d_in[4];
  const float* bb = (const float*)d_in[5];
  const float* bm = (const float*)d_in[6];
  const float* bv = (const float*)d_in[7];
  float* out = (float*)d_out;

  char* ws = (char*)d_ws;
  int4*           idx4 = (int4*)(ws + WS_IDX4);
  float4*         wgt4 = (float4*)(ws + WS_WGT4);
  unsigned short* xT   = (unsigned short*)(ws + WS_XT);
  unsigned short* xTlo = (unsigned short*)(ws + WS_XTLO);
  unsigned short* acw  = (unsigned short*)(ws + WS_ACW);
  unsigned short* apwh = (unsigned short*)(ws + WS_APWH);
  unsigned short* apwl = (unsigned short*)(ws + WS_APWL);
  float*          bns  = (float*)(ws + WS_BNS);
  float*          bnt  = (float*)(ws + WS_BNT);

  k_pre<<<712, 256, 0, stream>>>(cw, pw, bg, bb, bm, bv, acw, apwh, apwl, bns, bnt);
  k_trans<<<1600, 256, 0, stream>>>(x, xT, xTlo);
  k_offset<<<3200, 64, 0, stream>>>(xT, xTlo, apwh, apwl, pb, idx4, wgt4);
  k_main<<<1600, 256, 0, stream>>>(xT, acw, idx4, wgt4, bns, bnt, out);
}